// Round 2
// baseline (280.847 us; speedup 1.0000x reference)
//
#include <hip/hip_runtime.h>
#include <math.h>

#define N_CLASSES 100000
#define DIM 512
#define D4 (DIM / 4)          // 128 float4 per row
#define BATCH 16384
#define ALPHA 0.95f
#define ONE_M_ALPHA 0.05f
#define LOG_ALPHA (-0.051293294387550533f)   // ln(0.95)

// Phase A: last_occ[class] = max batch position b with i[b] == class.
// last_occ pre-initialized to -1 (0xFF memset); signed atomicMax with b>=0.
__global__ __launch_bounds__(256) void ema_last_occ_kernel(
        const int* __restrict__ idx,
        int* __restrict__ last_occ) {
    const int b = blockIdx.x * blockDim.x + threadIdx.x;
    if (b < BATCH) {
        atomicMax(&last_occ[idx[b]], b);
    }
}

// Phase B: out[b,:] = (alpha*centers[i[b],:] + (1-alpha)*x[last_occ[i[b]],:]) / c
//          c = 1 - alpha^(counts[i[b]] + 1)
// 256 threads/block = 2 rows/block, 128 lanes per row, one float4 per lane
// (16 B/lane, fully coalesced 2 KB per row).
__global__ __launch_bounds__(256) void ema_out_kernel(
        const int* __restrict__ idx,
        const float4* __restrict__ x4,
        const float4* __restrict__ centers4,
        const float* __restrict__ counts,
        const int* __restrict__ last_occ,
        float4* __restrict__ out4) {
    const int b = blockIdx.x * 2 + (threadIdx.x >> 7);   // row in batch
    const int d = threadIdx.x & 127;                     // float4 index in row

    const int row = idx[b];
    const int bl  = last_occ[row];                       // last occurrence of this class
    const float cnt  = counts[row] + 1.0f;
    const float invc = 1.0f / (1.0f - expf(LOG_ALPHA * cnt));

    const float4 cv = centers4[(size_t)row * D4 + d];
    const float4 xv = x4[(size_t)bl * D4 + d];

    float4 o;
    o.x = (ALPHA * cv.x + ONE_M_ALPHA * xv.x) * invc;
    o.y = (ALPHA * cv.y + ONE_M_ALPHA * xv.y) * invc;
    o.z = (ALPHA * cv.z + ONE_M_ALPHA * xv.z) * invc;
    o.w = (ALPHA * cv.w + ONE_M_ALPHA * xv.w) * invc;

    out4[(size_t)b * D4 + d] = o;
}

extern "C" void kernel_launch(void* const* d_in, const int* in_sizes, int n_in,
                              void* d_out, int out_size, void* d_ws, size_t ws_size,
                              hipStream_t stream) {
    const int*   idx     = (const int*)d_in[0];
    const float* x       = (const float*)d_in[1];
    const float* centers = (const float*)d_in[2];
    const float* counts  = (const float*)d_in[3];
    float*       out     = (float*)d_out;

    int* last_occ = (int*)d_ws;   // N_CLASSES ints = 400 KB scratch

    // init last_occ to -1 (0xFFFFFFFF); async memset is graph-capture safe.
    // (Do NOT rely on the harness 0xAA ws-poison being negative.)
    hipMemsetAsync(last_occ, 0xFF, (size_t)N_CLASSES * sizeof(int), stream);

    ema_last_occ_kernel<<<(BATCH + 255) / 256, 256, 0, stream>>>(idx, last_occ);

    ema_out_kernel<<<BATCH / 2, 256, 0, stream>>>(
        idx, (const float4*)x, (const float4*)centers, counts, last_occ,
        (float4*)out);
}

// Round 7
// 276.619 us; speedup vs baseline: 1.0153x; 1.0153x over previous
//
#include <hip/hip_runtime.h>
#include <math.h>

#define N_CLASSES 100000
#define DIM 512
#define D4 (DIM / 4)          // 128 float4 per row
#define BATCH 16384
#define ALPHA 0.95f
#define ONE_M_ALPHA 0.05f
#define LOG_ALPHA (-0.051293294387550533f)   // ln(0.95)

typedef __attribute__((ext_vector_type(4))) float f32x4;

// Phase A: last_occ[class] = max batch position b with i[b] == class.
// last_occ pre-initialized to -1 (0xFF memset); signed atomicMax with b>=0.
__global__ __launch_bounds__(256) void ema_last_occ_kernel(
        const int* __restrict__ idx,
        int* __restrict__ last_occ) {
    const int b = blockIdx.x * blockDim.x + threadIdx.x;
    if (b < BATCH) {
        atomicMax(&last_occ[idx[b]], b);
    }
}

// Phase B: out[b,:] = (alpha*centers[i[b],:] + (1-alpha)*x[last_occ[i[b]],:]) / c
//          c = 1 - alpha^(counts[i[b]] + 1)
// 512 threads/block = 4 rows/block, 128 lanes per row, one float4 per lane
// (16 B/lane; each row = 2 KB fully-coalesced, 2 waves per row).
// centers rows and out are touch-once -> nontemporal to skip cache allocation.
__global__ __launch_bounds__(512) void ema_out_kernel(
        const int* __restrict__ idx,
        const f32x4* __restrict__ x4,
        const f32x4* __restrict__ centers4,
        const float* __restrict__ counts,
        const int* __restrict__ last_occ,
        f32x4* __restrict__ out4) {
    const int b = blockIdx.x * 4 + (threadIdx.x >> 7);   // row in batch
    const int d = threadIdx.x & 127;                     // float4 index in row

    const int row = idx[b];
    // issue the centers gather immediately (independent of last_occ chain)
    const f32x4 cv = __builtin_nontemporal_load(&centers4[(size_t)row * D4 + d]);

    const int bl  = last_occ[row];                       // last occurrence of this class
    const float cnt  = counts[row] + 1.0f;
    const float invc = 1.0f / (1.0f - expf(LOG_ALPHA * cnt));

    const f32x4 xv = x4[(size_t)bl * D4 + d];

    f32x4 o;
    o.x = (ALPHA * cv.x + ONE_M_ALPHA * xv.x) * invc;
    o.y = (ALPHA * cv.y + ONE_M_ALPHA * xv.y) * invc;
    o.z = (ALPHA * cv.z + ONE_M_ALPHA * xv.z) * invc;
    o.w = (ALPHA * cv.w + ONE_M_ALPHA * xv.w) * invc;

    __builtin_nontemporal_store(o, &out4[(size_t)b * D4 + d]);
}

extern "C" void kernel_launch(void* const* d_in, const int* in_sizes, int n_in,
                              void* d_out, int out_size, void* d_ws, size_t ws_size,
                              hipStream_t stream) {
    const int*   idx     = (const int*)d_in[0];
    const float* x       = (const float*)d_in[1];
    const float* centers = (const float*)d_in[2];
    const float* counts  = (const float*)d_in[3];
    float*       out     = (float*)d_out;

    int* last_occ = (int*)d_ws;   // N_CLASSES ints = 400 KB scratch

    // init last_occ to -1 (0xFFFFFFFF); async memset is graph-capture safe.
    // (Do NOT rely on the harness 0xAA ws-poison being negative on the
    //  correctness call.)
    hipMemsetAsync(last_occ, 0xFF, (size_t)N_CLASSES * sizeof(int), stream);

    ema_last_occ_kernel<<<(BATCH + 255) / 256, 256, 0, stream>>>(idx, last_occ);

    ema_out_kernel<<<BATCH / 4, 512, 0, stream>>>(
        idx, (const f32x4*)x, (const f32x4*)centers, counts, last_occ,
        (f32x4*)out);
}